// Round 1
// baseline (372.375 us; speedup 1.0000x reference)
//
#include <hip/hip_runtime.h>
#include <stdint.h>

#define NN 16384
#define EE 262144
#define DD 256

typedef float f32x4 __attribute__((ext_vector_type(4)));
typedef short s16x8 __attribute__((ext_vector_type(8)));
typedef unsigned short u16x4 __attribute__((ext_vector_type(4)));
typedef unsigned short u16x8 __attribute__((ext_vector_type(8)));

#define AS1 __attribute__((address_space(1)))
#define AS3 __attribute__((address_space(3)))

__device__ __forceinline__ float bf2f(unsigned short u) {
  union { unsigned int i; float f; } v; v.i = ((unsigned int)u) << 16; return v.f;
}
__device__ __forceinline__ unsigned short f2bf(float f) {
  union { float f; unsigned int i; } v; v.f = f;
  unsigned int r = v.i + 0x7fffu + ((v.i >> 16) & 1u);
  return (unsigned short)(r >> 16);
}
__device__ __forceinline__ float lrelu(float x) { return x > 0.f ? x : 0.2f * x; }

// ---------------------------------------------------------------------------
// prep: weight algebra.  BcatT[n][k] (bf16, [1024][256]) = columns of
// [Wn | Wv | Wq@A1_1 | Wk@A1_2] transposed (n-major, k-contiguous, as the
// MFMA B-operand needs).  WeaT[c][k] = (We@A1_3)^T (bf16 [256][64]).
// bcomb = bq@A1_1 + bk@A1_2 + be@A1_3 + a1.  bcat = [bn, bv, 0, 0].
// ---------------------------------------------------------------------------
__global__ __launch_bounds__(256) void prep_kernel(
    const float* __restrict__ Wn, const float* __restrict__ bn,
    const float* __restrict__ Wq, const float* __restrict__ bq,
    const float* __restrict__ Wk, const float* __restrict__ bk,
    const float* __restrict__ Wv, const float* __restrict__ bv,
    const float* __restrict__ We, const float* __restrict__ be,
    const float* __restrict__ A1, const float* __restrict__ a1,
    unsigned short* __restrict__ BcatT, float* __restrict__ bcat,
    unsigned short* __restrict__ WeaT, float* __restrict__ bcomb)
{
  const int b = blockIdx.x, t = threadIdx.x;
  if (b < 256) {                 // Wqa, k = b, n = t
    float acc = 0.f;
    for (int j = 0; j < 256; ++j) acc += Wq[b * 256 + j] * A1[j * 256 + t];
    BcatT[(512 + t) * 256 + b] = f2bf(acc);
  } else if (b < 512) {          // Wka
    int k = b - 256; float acc = 0.f;
    for (int j = 0; j < 256; ++j) acc += Wk[k * 256 + j] * A1[(256 + j) * 256 + t];
    BcatT[(768 + t) * 256 + k] = f2bf(acc);
  } else if (b < 576) {          // WeaT, k = b-512 in [0,64)
    int k = b - 512; float acc = 0.f;
    for (int j = 0; j < 256; ++j) acc += We[k * 256 + j] * A1[(512 + j) * 256 + t];
    WeaT[t * 64 + k] = f2bf(acc);
  } else if (b == 576) {         // bcomb
    float acc = a1[t];
    for (int j = 0; j < 256; ++j) {
      acc += bq[j] * A1[j * 256 + t];
      acc += bk[j] * A1[(256 + j) * 256 + t];
      acc += be[j] * A1[(512 + j) * 256 + t];
    }
    bcomb[t] = acc;
  } else if (b < 705) {          // transpose Wn, Wv into BcatT rows 0..511
    int b2 = b - 577;
    for (int rr = 0; rr < 4; ++rr) {
      int np = b2 * 4 + rr;
      float v = (np < 256) ? Wn[t * 256 + np] : Wv[t * 256 + (np - 256)];
      BcatT[np * 256 + t] = f2bf(v);
    }
  } else {                       // b == 705: bcat
    bcat[t] = bn[t];
    bcat[256 + t] = bv[t];
    bcat[512 + t] = 0.f;
    bcat[768 + t] = 0.f;
  }
}

// nf f32 -> bf16
__global__ __launch_bounds__(256) void conv_bf16_kernel(
    const float* __restrict__ in, unsigned short* __restrict__ o)
{
  size_t i = (size_t)blockIdx.x * 256 + threadIdx.x;
  const f32x4* p = (const f32x4*)(in + i * 8);
  f32x4 a = p[0], b = p[1];
  u16x8 r = { f2bf(a[0]), f2bf(a[1]), f2bf(a[2]), f2bf(a[3]),
              f2bf(b[0]), f2bf(b[1]), f2bf(b[2]), f2bf(b[3]) };
  *(u16x8*)(o + i * 8) = r;
}

// ---------------------------------------------------------------------------
// node GEMM: [16384,256]@[256,1024] bf16 MFMA.
// Out cols 0-255: h (f32), 256-511: v (bf16), 512-767: Qa, 768-1023: Ka.
// 128x128 tile, BK=64, 4 waves (2x2 of 64x64), global_load_lds staging,
// st-style XOR swizzle (slot ^= row&7) on 128B rows for conflict-free
// ds_read_b128 fragments.
// ---------------------------------------------------------------------------
__global__ __launch_bounds__(256, 1) void node_gemm_kernel(
    const unsigned short* __restrict__ Abf,   // nf bf16 [16384][256]
    const unsigned short* __restrict__ BT,    // BcatT  [1024][256]
    const float* __restrict__ bias,           // bcat [1024]
    float* __restrict__ hout, unsigned short* __restrict__ vout,
    unsigned short* __restrict__ Qa, unsigned short* __restrict__ Ka)
{
  __shared__ __align__(16) unsigned short Al[128 * 64];
  __shared__ __align__(16) unsigned short Bl[128 * 64];
  const int t = threadIdx.x;
  const int wid = t >> 6, lane = t & 63;
  const int quad = lane >> 4, l15 = lane & 15;
  const int mblk = blockIdx.x & 127, nblk = blockIdx.x >> 7;
  const int m0 = mblk * 128, n0 = nblk * 128;
  const int mh = wid >> 1, nh = wid & 1;
  const int srow = lane >> 3, sslot = lane & 7;

  f32x4 acc[4][4];
  #pragma unroll
  for (int i = 0; i < 4; ++i)
    #pragma unroll
    for (int j = 0; j < 4; ++j) acc[i][j] = (f32x4){0.f, 0.f, 0.f, 0.f};

  for (int ks = 0; ks < 4; ++ks) {
    const int k0 = ks * 64;
    #pragma unroll
    for (int j = 0; j < 4; ++j) {
      int cj = wid * 4 + j;
      int row = cj * 8 + srow;
      const unsigned short* ga =
          Abf + (size_t)(m0 + row) * 256 + k0 + ((sslot ^ (row & 7)) * 8);
      __builtin_amdgcn_global_load_lds((AS1 const void*)ga,
                                       (AS3 void*)(Al + cj * 512), 16, 0, 0);
      const unsigned short* gb =
          BT + (size_t)(n0 + row) * 256 + k0 + ((sslot ^ (row & 7)) * 8);
      __builtin_amdgcn_global_load_lds((AS1 const void*)gb,
                                       (AS3 void*)(Bl + cj * 512), 16, 0, 0);
    }
    __syncthreads();
    s16x8 af[4][2], bfr[4][2];
    #pragma unroll
    for (int mt = 0; mt < 4; ++mt) {
      int row = mh * 64 + mt * 16 + l15;
      #pragma unroll
      for (int kk = 0; kk < 2; ++kk) {
        int s = (kk * 4 + quad) ^ (row & 7);
        af[mt][kk] = *(const s16x8*)(Al + row * 64 + s * 8);
      }
    }
    #pragma unroll
    for (int nt = 0; nt < 4; ++nt) {
      int row = nh * 64 + nt * 16 + l15;
      #pragma unroll
      for (int kk = 0; kk < 2; ++kk) {
        int s = (kk * 4 + quad) ^ (row & 7);
        bfr[nt][kk] = *(const s16x8*)(Bl + row * 64 + s * 8);
      }
    }
    #pragma unroll
    for (int mt = 0; mt < 4; ++mt)
      #pragma unroll
      for (int nt = 0; nt < 4; ++nt) {
        acc[mt][nt] = __builtin_amdgcn_mfma_f32_16x16x32_bf16(
            af[mt][0], bfr[nt][0], acc[mt][nt], 0, 0, 0);
        acc[mt][nt] = __builtin_amdgcn_mfma_f32_16x16x32_bf16(
            af[mt][1], bfr[nt][1], acc[mt][nt], 0, 0, 0);
      }
    __syncthreads();
  }

  #pragma unroll
  for (int nt = 0; nt < 4; ++nt) {
    int n = n0 + nh * 64 + nt * 16 + l15;
    float bb = bias[n];
    int seg = n >> 8;
    int ncol = n & 255;
    #pragma unroll
    for (int mt = 0; mt < 4; ++mt) {
      int m = m0 + mh * 64 + mt * 16 + quad * 4;
      f32x4 a = acc[mt][nt];
      #pragma unroll
      for (int r = 0; r < 4; ++r) {
        float val = a[r] + bb;
        size_t idx = (size_t)(m + r) * 256 + ncol;
        if (seg == 0) hout[idx] = val;
        else if (seg == 1) vout[idx] = f2bf(val);
        else if (seg == 2) Qa[idx] = f2bf(val);
        else Ka[idx] = f2bf(val);
      }
    }
  }
}

// ---------------------------------------------------------------------------
// edge scores: per WG 64 edges.  MFMA computes Ea = ef@WeaT^T with
// M = channel, N = edge (so the Qa/Ka row-gathers are 8B/lane contiguous);
// WeaT A-fragments live in registers (reused across all edges).  Then
// mid = lrelu(Ea + Qa[src] + Ka[tgt] + bcomb), s8 = mid@A2 + a2, lrelu,
// head-mean, p = exp(s).  Also builds the src histogram for CSR.
// ---------------------------------------------------------------------------
__global__ __launch_bounds__(256, 1) void edge_scores_kernel(
    const int* __restrict__ eidx, const float* __restrict__ ef,
    const unsigned short* __restrict__ Qa, const unsigned short* __restrict__ Ka,
    const unsigned short* __restrict__ WeaT, const float* __restrict__ bcomb,
    const float* __restrict__ A2, const float* __restrict__ a2g,
    float* __restrict__ P, float* __restrict__ Z, int* __restrict__ deg)
{
  __shared__ __align__(16) unsigned short efl[64 * 64];  // swizzled bf16
  __shared__ __align__(16) float A2l[256 * 12];          // stride 12 (pad)
  __shared__ __align__(16) float pl[4 * 64 * 8];
  __shared__ int srcl[64], tgtl[64];
  const int t = threadIdx.x;
  const int wid = t >> 6, lane = t & 63, quad = lane >> 4, l15 = lane & 15;
  const int eb = blockIdx.x * 64;

  {  // stage A2 (256x8 f32) with padded stride
    const f32x4* sp = (const f32x4*)(A2 + t * 8);
    f32x4 x0 = sp[0], x1 = sp[1];
    *(f32x4*)&A2l[t * 12] = x0;
    *(f32x4*)&A2l[t * 12 + 4] = x1;
  }
  if (t < 64) { int s_ = eidx[eb + t]; srcl[t] = s_; atomicAdd(&deg[s_], 1); }
  else if (t < 128) { tgtl[t - 64] = eidx[EE + eb + (t - 64)]; }
  {  // stage ef tile [64 edges][64 feat] -> bf16, slot-XOR swizzled
    int r = t >> 2, q4 = t & 3;
    const f32x4* sp = (const f32x4*)(ef + (size_t)(eb + r) * 64 + q4 * 16);
    f32x4 v0 = sp[0], v1 = sp[1], v2 = sp[2], v3 = sp[3];
    u16x8 w0 = { f2bf(v0[0]), f2bf(v0[1]), f2bf(v0[2]), f2bf(v0[3]),
                 f2bf(v1[0]), f2bf(v1[1]), f2bf(v1[2]), f2bf(v1[3]) };
    u16x8 w1 = { f2bf(v2[0]), f2bf(v2[1]), f2bf(v2[2]), f2bf(v2[3]),
                 f2bf(v3[0]), f2bf(v3[1]), f2bf(v3[2]), f2bf(v3[3]) };
    int s0_ = (2 * q4) ^ (r & 7), s1_ = (2 * q4 + 1) ^ (r & 7);
    *(u16x8*)&efl[r * 64 + s0_ * 8] = w0;
    *(u16x8*)&efl[r * 64 + s1_ * 8] = w1;
  }
  // A fragments (weights) + bias, kept in registers across all edges
  s16x8 af[4][2];
  f32x4 bc[4];
  #pragma unroll
  for (int ct = 0; ct < 4; ++ct) {
    int ch = wid * 64 + ct * 16 + l15;
    af[ct][0] = *(const s16x8*)(WeaT + ch * 64 + quad * 8);
    af[ct][1] = *(const s16x8*)(WeaT + ch * 64 + 32 + quad * 8);
    bc[ct] = *(const f32x4*)(bcomb + wid * 64 + ct * 16 + quad * 4);
  }
  __syncthreads();

  f32x4 acc[4][4];  // [ct][et]
  #pragma unroll
  for (int i = 0; i < 4; ++i)
    #pragma unroll
    for (int j = 0; j < 4; ++j) acc[i][j] = (f32x4){0.f, 0.f, 0.f, 0.f};

  #pragma unroll
  for (int et = 0; et < 4; ++et) {
    int e = et * 16 + l15;
    s16x8 b0 = *(const s16x8*)(efl + e * 64 + ((quad ^ (e & 7)) * 8));
    s16x8 b1 = *(const s16x8*)(efl + e * 64 + (((4 + quad) ^ (e & 7)) * 8));
    #pragma unroll
    for (int ct = 0; ct < 4; ++ct) {
      acc[ct][et] = __builtin_amdgcn_mfma_f32_16x16x32_bf16(af[ct][0], b0, acc[ct][et], 0, 0, 0);
      acc[ct][et] = __builtin_amdgcn_mfma_f32_16x16x32_bf16(af[ct][1], b1, acc[ct][et], 0, 0, 0);
    }
  }
  // gather Qa[src], Ka[tgt]; mid = lrelu(sum + bias)
  #pragma unroll
  for (int et = 0; et < 4; ++et) {
    int e = et * 16 + l15;
    int se = srcl[e], te = tgtl[e];
    #pragma unroll
    for (int ct = 0; ct < 4; ++ct) {
      u16x4 qv = *(const u16x4*)(Qa + (size_t)se * 256 + wid * 64 + ct * 16 + quad * 4);
      u16x4 kv = *(const u16x4*)(Ka + (size_t)te * 256 + wid * 64 + ct * 16 + quad * 4);
      f32x4 x = acc[ct][et];
      #pragma unroll
      for (int r = 0; r < 4; ++r) {
        float xv = x[r] + bf2f(qv[r]) + bf2f(kv[r]) + bc[ct][r];
        x[r] = lrelu(xv);
      }
      acc[ct][et] = x;
    }
  }
  // mid @ A2: per-lane partials over this lane's 16 channels
  float part[4][8];
  #pragma unroll
  for (int i = 0; i < 4; ++i)
    #pragma unroll
    for (int j = 0; j < 8; ++j) part[i][j] = 0.f;
  #pragma unroll
  for (int ct = 0; ct < 4; ++ct) {
    int chb = wid * 64 + ct * 16 + quad * 4;
    #pragma unroll
    for (int r = 0; r < 4; ++r) {
      f32x4 w0 = *(const f32x4*)&A2l[(chb + r) * 12];
      f32x4 w1 = *(const f32x4*)&A2l[(chb + r) * 12 + 4];
      #pragma unroll
      for (int et = 0; et < 4; ++et) {
        float m = acc[ct][et][r];
        part[et][0] += m * w0[0]; part[et][1] += m * w0[1];
        part[et][2] += m * w0[2]; part[et][3] += m * w0[3];
        part[et][4] += m * w1[0]; part[et][5] += m * w1[1];
        part[et][6] += m * w1[2]; part[et][7] += m * w1[3];
      }
    }
  }
  #pragma unroll
  for (int et = 0; et < 4; ++et)
    #pragma unroll
    for (int hh = 0; hh < 8; ++hh) {
      part[et][hh] += __shfl_xor(part[et][hh], 16);
      part[et][hh] += __shfl_xor(part[et][hh], 32);
    }
  if (quad == 0) {
    #pragma unroll
    for (int et = 0; et < 4; ++et) {
      f32x4 p0 = { part[et][0], part[et][1], part[et][2], part[et][3] };
      f32x4 p1 = { part[et][4], part[et][5], part[et][6], part[et][7] };
      int e = et * 16 + l15;
      *(f32x4*)&pl[(wid * 64 + e) * 8] = p0;
      *(f32x4*)&pl[(wid * 64 + e) * 8 + 4] = p1;
    }
  }
  __syncthreads();
  if (t < 64) {  // finalize 64 edges on wave 0
    float tot[8] = {0.f, 0.f, 0.f, 0.f, 0.f, 0.f, 0.f, 0.f};
    #pragma unroll
    for (int w2 = 0; w2 < 4; ++w2)
      #pragma unroll
      for (int hh = 0; hh < 8; ++hh) tot[hh] += pl[(w2 * 64 + t) * 8 + hh];
    float sacc = 0.f;
    #pragma unroll
    for (int hh = 0; hh < 8; ++hh) sacc += lrelu(tot[hh] + a2g[hh]);
    float p = __expf(sacc * 0.125f);
    P[eb + t] = p;
    #pragma unroll
    for (int d = 1; d < 64; d <<= 1) p += __shfl_xor(p, d);
    if (t == 0) atomicAdd(Z, p);
  }
}

// CSR scan: 1 WG, 256 threads, 64 bins each
__global__ __launch_bounds__(256) void scan_kernel(
    const int* __restrict__ deg, int* __restrict__ startA, int* __restrict__ cursor)
{
  __shared__ int ls[256];
  int t = threadIdx.x;
  int base = t * 64;
  int s = 0;
  for (int i = 0; i < 64; ++i) s += deg[base + i];
  ls[t] = s;
  __syncthreads();
  for (int d = 1; d < 256; d <<= 1) {
    int v = ls[t];
    if (t >= d) v += ls[t - d];
    __syncthreads();
    ls[t] = v;
    __syncthreads();
  }
  int run = ls[t] - s;
  for (int i = 0; i < 64; ++i) {
    int dv = deg[base + i];
    startA[base + i] = run;
    cursor[base + i] = run;
    run += dv;
  }
  if (t == 255) startA[NN] = run;
}

__global__ __launch_bounds__(256) void perm_kernel(
    const int* __restrict__ eidx, int* __restrict__ cursor, int* __restrict__ perm)
{
  int e = blockIdx.x * 256 + threadIdx.x;
  int s = eidx[e];
  int pos = atomicAdd(&cursor[s], 1);
  perm[pos] = e;
}

// per-node accumulate + residual + LayerNorm.  1 wave per node.
__global__ __launch_bounds__(64) void scatter_ln_kernel(
    const int* __restrict__ perm, const int* __restrict__ startA,
    const float* __restrict__ P, const float* __restrict__ Zp,
    const int* __restrict__ tgt, const unsigned short* __restrict__ vbuf,
    const float* __restrict__ hbuf, const float* __restrict__ gamma,
    const float* __restrict__ beta, float* __restrict__ out)
{
  int n = blockIdx.x, lane = threadIdx.x;
  float invZ = 1.f / Zp[0];
  int s0 = startA[n], s1 = startA[n + 1];
  float a0 = 0.f, a1_ = 0.f, a2_ = 0.f, a3_ = 0.f;
  for (int i = s0; i < s1; ++i) {
    int e = perm[i];
    float w = P[e] * invZ;
    int te = tgt[e];
    u16x4 vv = *(const u16x4*)(vbuf + (size_t)te * 256 + lane * 4);
    a0 += w * bf2f(vv[0]); a1_ += w * bf2f(vv[1]);
    a2_ += w * bf2f(vv[2]); a3_ += w * bf2f(vv[3]);
  }
  f32x4 hv = *(const f32x4*)(hbuf + (size_t)n * 256 + lane * 4);
  float x0 = hv[0] + a0, x1 = hv[1] + a1_, x2 = hv[2] + a2_, x3 = hv[3] + a3_;
  float sum = x0 + x1 + x2 + x3;
  float sq = x0 * x0 + x1 * x1 + x2 * x2 + x3 * x3;
  #pragma unroll
  for (int d = 1; d < 64; d <<= 1) { sum += __shfl_xor(sum, d); sq += __shfl_xor(sq, d); }
  float mu = sum * (1.f / 256.f);
  float var = sq * (1.f / 256.f) - mu * mu;
  float rstd = rsqrtf(var + 1e-5f);
  f32x4 g = *(const f32x4*)(gamma + lane * 4);
  f32x4 b = *(const f32x4*)(beta + lane * 4);
  f32x4 o;
  o[0] = (x0 - mu) * rstd * g[0] + b[0];
  o[1] = (x1 - mu) * rstd * g[1] + b[1];
  o[2] = (x2 - mu) * rstd * g[2] + b[2];
  o[3] = (x3 - mu) * rstd * g[3] + b[3];
  *(f32x4*)(out + (size_t)n * 256 + lane * 4) = o;
}

extern "C" void kernel_launch(void* const* d_in, const int* in_sizes, int n_in,
                              void* d_out, int out_size, void* d_ws, size_t ws_size,
                              hipStream_t stream)
{
  (void)in_sizes; (void)n_in; (void)out_size; (void)ws_size;
  const float* nf    = (const float*)d_in[0];
  const int*   eidx  = (const int*)  d_in[1];
  const float* ef    = (const float*)d_in[2];
  const float* Wn    = (const float*)d_in[3];
  const float* bn    = (const float*)d_in[4];
  const float* Wq    = (const float*)d_in[5];
  const float* bq    = (const float*)d_in[6];
  const float* Wk    = (const float*)d_in[7];
  const float* bk    = (const float*)d_in[8];
  const float* Wv    = (const float*)d_in[9];
  const float* bv    = (const float*)d_in[10];
  const float* We    = (const float*)d_in[11];
  const float* be    = (const float*)d_in[12];
  const float* A1    = (const float*)d_in[13];
  const float* a1    = (const float*)d_in[14];
  const float* A2    = (const float*)d_in[15];
  const float* a2    = (const float*)d_in[16];
  const float* gamma = (const float*)d_in[17];
  const float* beta  = (const float*)d_in[18];
  float* out = (float*)d_out;

  char* ws = (char*)d_ws;
  size_t off = 0;
  auto take = [&](size_t bytes) {
    size_t r = off; off += (bytes + 255) & ~(size_t)255; return r;
  };
  float* Z       = (float*)(ws + take(16));
  int*   deg     = (int*)  (ws + take((size_t)NN * 4));
  int*   startA  = (int*)  (ws + take((size_t)(NN + 1) * 4));
  int*   cursor  = (int*)  (ws + take((size_t)NN * 4));
  int*   perm    = (int*)  (ws + take((size_t)EE * 4));
  float* P       = (float*)(ws + take((size_t)EE * 4));
  float* hbuf    = (float*)(ws + take((size_t)NN * DD * 4));
  unsigned short* vbuf  = (unsigned short*)(ws + take((size_t)NN * DD * 2));
  unsigned short* QaB   = (unsigned short*)(ws + take((size_t)NN * DD * 2));
  unsigned short* KaB   = (unsigned short*)(ws + take((size_t)NN * DD * 2));
  unsigned short* BcatT = (unsigned short*)(ws + take((size_t)1024 * 256 * 2));
  float* bcat    = (float*)(ws + take(1024 * 4));
  unsigned short* WeaT  = (unsigned short*)(ws + take((size_t)256 * 64 * 2));
  float* bcomb   = (float*)(ws + take(256 * 4));
  unsigned short* nfb   = (unsigned short*)(ws + take((size_t)NN * DD * 2));

  // zero Z + deg (first 256 + 64K bytes of ws)
  hipMemsetAsync(d_ws, 0, 256 + (size_t)NN * 4, stream);

  prep_kernel<<<706, 256, 0, stream>>>(Wn, bn, Wq, bq, Wk, bk, Wv, bv,
                                       We, be, A1, a1, BcatT, bcat, WeaT, bcomb);
  conv_bf16_kernel<<<(NN * DD / 8) / 256, 256, 0, stream>>>(nf, nfb);
  node_gemm_kernel<<<1024, 256, 0, stream>>>(nfb, BcatT, bcat, hbuf, vbuf, QaB, KaB);
  edge_scores_kernel<<<EE / 64, 256, 0, stream>>>(eidx, ef, QaB, KaB, WeaT,
                                                  bcomb, A2, a2, P, Z, deg);
  scan_kernel<<<1, 256, 0, stream>>>(deg, startA, cursor);
  perm_kernel<<<EE / 256, 256, 0, stream>>>(eidx, cursor, perm);
  scatter_ln_kernel<<<NN, 64, 0, stream>>>(perm, startA, P, Z, eidx + EE,
                                           vbuf, hbuf, gamma, beta, out);
}

// Round 2
// 347.860 us; speedup vs baseline: 1.0705x; 1.0705x over previous
//
#include <hip/hip_runtime.h>
#include <stdint.h>

#define NN 16384
#define EE 262144
#define DD 256

typedef float f32x4 __attribute__((ext_vector_type(4)));
typedef short s16x8 __attribute__((ext_vector_type(8)));
typedef unsigned short u16x4 __attribute__((ext_vector_type(4)));
typedef unsigned short u16x8 __attribute__((ext_vector_type(8)));

#define AS1 __attribute__((address_space(1)))
#define AS3 __attribute__((address_space(3)))

__device__ __forceinline__ float bf2f(unsigned short u) {
  union { unsigned int i; float f; } v; v.i = ((unsigned int)u) << 16; return v.f;
}
__device__ __forceinline__ unsigned short f2bf(float f) {
  union { float f; unsigned int i; } v; v.f = f;
  unsigned int r = v.i + 0x7fffu + ((v.i >> 16) & 1u);
  return (unsigned short)(r >> 16);
}
__device__ __forceinline__ float lrelu(float x) { return x > 0.f ? x : 0.2f * x; }

// channel-storage permutation (involution): swap ct<->quad fields in low 6 bits.
// Storage row M (WeaT rows, bcomb, A2p) holds channel chanperm(M) of the
// natural (Qa/Ka column) basis; chosen so each lane's 16 accumulator channels
// are 16 CONTIGUOUS Qa/Ka columns.
__device__ __forceinline__ int chanperm(int c) {
  int hi = c & ~63, loc = c & 63;
  int ct = loc >> 4, quad = (loc >> 2) & 3, r = loc & 3;
  return hi | (quad * 16 + ct * 4 + r);
}

// ---------------------------------------------------------------------------
// prep: weight algebra.  BcatT[n][k] (bf16 [1024][256]) = [Wn|Wv|Wq@A1_1|Wk@A1_2]^T.
// WeaT[M][k] = (We@A1_3)^T row chanperm(M).  bcomb[M] = bias of chan chanperm(M).
// A2p[M] = A2 row chanperm(M).  bcat = [bn, bv, 0, 0].
// ---------------------------------------------------------------------------
__global__ __launch_bounds__(256) void prep_kernel(
    const float* __restrict__ Wn, const float* __restrict__ bn,
    const float* __restrict__ Wq, const float* __restrict__ bq,
    const float* __restrict__ Wk, const float* __restrict__ bk,
    const float* __restrict__ Wv, const float* __restrict__ bv,
    const float* __restrict__ We, const float* __restrict__ be,
    const float* __restrict__ A1, const float* __restrict__ a1,
    const float* __restrict__ A2,
    unsigned short* __restrict__ BcatT, float* __restrict__ bcat,
    unsigned short* __restrict__ WeaT, float* __restrict__ bcomb,
    float* __restrict__ A2p)
{
  const int b = blockIdx.x, t = threadIdx.x;
  if (b < 256) {                 // Wqa, k = b, n = t
    float acc = 0.f;
    for (int j = 0; j < 256; ++j) acc += Wq[b * 256 + j] * A1[j * 256 + t];
    BcatT[(512 + t) * 256 + b] = f2bf(acc);
  } else if (b < 512) {          // Wka
    int k = b - 256; float acc = 0.f;
    for (int j = 0; j < 256; ++j) acc += Wk[k * 256 + j] * A1[(256 + j) * 256 + t];
    BcatT[(768 + t) * 256 + k] = f2bf(acc);
  } else if (b < 576) {          // WeaT row chanperm(t), col k = b-512
    int k = b - 512; float acc = 0.f;
    for (int j = 0; j < 256; ++j) acc += We[k * 256 + j] * A1[(512 + j) * 256 + t];
    WeaT[chanperm(t) * 64 + k] = f2bf(acc);
  } else if (b == 576) {         // bcomb (m-order)
    float acc = a1[t];
    for (int j = 0; j < 256; ++j) {
      acc += bq[j] * A1[j * 256 + t];
      acc += bk[j] * A1[(256 + j) * 256 + t];
      acc += be[j] * A1[(512 + j) * 256 + t];
    }
    bcomb[chanperm(t)] = acc;
  } else if (b < 705) {          // transpose Wn, Wv into BcatT rows 0..511
    int b2 = b - 577;
    for (int rr = 0; rr < 4; ++rr) {
      int np = b2 * 4 + rr;
      float v = (np < 256) ? Wn[t * 256 + np] : Wv[t * 256 + (np - 256)];
      BcatT[np * 256 + t] = f2bf(v);
    }
  } else if (b == 705) {         // bcat
    bcat[t] = bn[t];
    bcat[256 + t] = bv[t];
    bcat[512 + t] = 0.f;
    bcat[768 + t] = 0.f;
  } else {                       // b == 706: A2p (m-order)
    int m = chanperm(t);
    for (int j = 0; j < 8; ++j) A2p[m * 8 + j] = A2[t * 8 + j];
  }
}

// nf f32 -> bf16, plus src-degree histogram (fused)
__global__ __launch_bounds__(256) void conv_hist_kernel(
    const float* __restrict__ in, unsigned short* __restrict__ o,
    const int* __restrict__ eidx, int* __restrict__ deg)
{
  size_t i = (size_t)blockIdx.x * 256 + threadIdx.x;
  const f32x4* p = (const f32x4*)(in + i * 8);
  f32x4 a = p[0], b = p[1];
  u16x8 r = { f2bf(a[0]), f2bf(a[1]), f2bf(a[2]), f2bf(a[3]),
              f2bf(b[0]), f2bf(b[1]), f2bf(b[2]), f2bf(b[3]) };
  *(u16x8*)(o + i * 8) = r;
  if (blockIdx.x < EE / 256) {
    int e = blockIdx.x * 256 + threadIdx.x;
    atomicAdd(&deg[eidx[e]], 1);
  }
}

// ---------------------------------------------------------------------------
// node GEMM: [16384,256]@[256,1024] bf16 MFMA (unchanged from r1, verified).
// ---------------------------------------------------------------------------
__global__ __launch_bounds__(256, 1) void node_gemm_kernel(
    const unsigned short* __restrict__ Abf,
    const unsigned short* __restrict__ BT,
    const float* __restrict__ bias,
    float* __restrict__ hout, unsigned short* __restrict__ vout,
    unsigned short* __restrict__ Qa, unsigned short* __restrict__ Ka)
{
  __shared__ __align__(16) unsigned short Al[128 * 64];
  __shared__ __align__(16) unsigned short Bl[128 * 64];
  const int t = threadIdx.x;
  const int wid = t >> 6, lane = t & 63;
  const int quad = lane >> 4, l15 = lane & 15;
  const int mblk = blockIdx.x & 127, nblk = blockIdx.x >> 7;
  const int m0 = mblk * 128, n0 = nblk * 128;
  const int mh = wid >> 1, nh = wid & 1;
  const int srow = lane >> 3, sslot = lane & 7;

  f32x4 acc[4][4];
  #pragma unroll
  for (int i = 0; i < 4; ++i)
    #pragma unroll
    for (int j = 0; j < 4; ++j) acc[i][j] = (f32x4){0.f, 0.f, 0.f, 0.f};

  for (int ks = 0; ks < 4; ++ks) {
    const int k0 = ks * 64;
    #pragma unroll
    for (int j = 0; j < 4; ++j) {
      int cj = wid * 4 + j;
      int row = cj * 8 + srow;
      const unsigned short* ga =
          Abf + (size_t)(m0 + row) * 256 + k0 + ((sslot ^ (row & 7)) * 8);
      __builtin_amdgcn_global_load_lds((AS1 const void*)ga,
                                       (AS3 void*)(Al + cj * 512), 16, 0, 0);
      const unsigned short* gb =
          BT + (size_t)(n0 + row) * 256 + k0 + ((sslot ^ (row & 7)) * 8);
      __builtin_amdgcn_global_load_lds((AS1 const void*)gb,
                                       (AS3 void*)(Bl + cj * 512), 16, 0, 0);
    }
    __syncthreads();
    s16x8 af[4][2], bfr[4][2];
    #pragma unroll
    for (int mt = 0; mt < 4; ++mt) {
      int row = mh * 64 + mt * 16 + l15;
      #pragma unroll
      for (int kk = 0; kk < 2; ++kk) {
        int s = (kk * 4 + quad) ^ (row & 7);
        af[mt][kk] = *(const s16x8*)(Al + row * 64 + s * 8);
      }
    }
    #pragma unroll
    for (int nt = 0; nt < 4; ++nt) {
      int row = nh * 64 + nt * 16 + l15;
      #pragma unroll
      for (int kk = 0; kk < 2; ++kk) {
        int s = (kk * 4 + quad) ^ (row & 7);
        bfr[nt][kk] = *(const s16x8*)(Bl + row * 64 + s * 8);
      }
    }
    #pragma unroll
    for (int mt = 0; mt < 4; ++mt)
      #pragma unroll
      for (int nt = 0; nt < 4; ++nt) {
        acc[mt][nt] = __builtin_amdgcn_mfma_f32_16x16x32_bf16(
            af[mt][0], bfr[nt][0], acc[mt][nt], 0, 0, 0);
        acc[mt][nt] = __builtin_amdgcn_mfma_f32_16x16x32_bf16(
            af[mt][1], bfr[nt][1], acc[mt][nt], 0, 0, 0);
      }
    __syncthreads();
  }

  #pragma unroll
  for (int nt = 0; nt < 4; ++nt) {
    int n = n0 + nh * 64 + nt * 16 + l15;
    float bb = bias[n];
    int seg = n >> 8;
    int ncol = n & 255;
    #pragma unroll
    for (int mt = 0; mt < 4; ++mt) {
      int m = m0 + mh * 64 + mt * 16 + quad * 4;
      f32x4 a = acc[mt][nt];
      #pragma unroll
      for (int r = 0; r < 4; ++r) {
        float val = a[r] + bb;
        size_t idx = (size_t)(m + r) * 256 + ncol;
        if (seg == 0) hout[idx] = val;
        else if (seg == 1) vout[idx] = f2bf(val);
        else if (seg == 2) Qa[idx] = f2bf(val);
        else Ka[idx] = f2bf(val);
      }
    }
  }
}

// CSR scan: 1 WG, deg kept in registers as int4
__global__ __launch_bounds__(256) void scan_kernel(
    const int* __restrict__ deg, int* __restrict__ startA, int* __restrict__ cursor)
{
  __shared__ int ls[256];
  const int t = threadIdx.x;
  int4 d[16];
  int s = 0;
  #pragma unroll
  for (int i = 0; i < 16; ++i) {
    d[i] = ((const int4*)deg)[t * 16 + i];
    s += d[i].x + d[i].y + d[i].z + d[i].w;
  }
  ls[t] = s;
  __syncthreads();
  for (int dd = 1; dd < 256; dd <<= 1) {
    int v = ls[t];
    if (t >= dd) v += ls[t - dd];
    __syncthreads();
    ls[t] = v;
    __syncthreads();
  }
  int run = ls[t] - s;
  #pragma unroll
  for (int i = 0; i < 16; ++i) {
    int4 o;
    o.x = run; run += d[i].x;
    o.y = run; run += d[i].y;
    o.z = run; run += d[i].z;
    o.w = run; run += d[i].w;
    ((int4*)startA)[t * 16 + i] = o;
    ((int4*)cursor)[t * 16 + i] = o;
  }
  if (t == 255) startA[NN] = run;
}

// build permuted edge arrays: position i (CSR by src) <- edge e
__global__ __launch_bounds__(256) void perm_kernel(
    const int* __restrict__ eidx, int* __restrict__ cursor,
    int* __restrict__ perm, int* __restrict__ srcp, int* __restrict__ tgtp)
{
  int e = blockIdx.x * 256 + threadIdx.x;
  int s = eidx[e], tg = eidx[EE + e];
  int pos = atomicAdd(&cursor[s], 1);
  perm[pos] = e;
  srcp[pos] = s;
  tgtp[pos] = tg;
}

// ---------------------------------------------------------------------------
// edge scores, processed in src-grouped (CSR) order.
// Gathers (2x16B per table per edge) INITIALIZE the MFMA accumulator; MFMA
// adds Ea on top; bias added pre-lrelu from LDS.  Writes Pp[i] (CSR order).
// ---------------------------------------------------------------------------
__global__ __launch_bounds__(256, 4) void edge_scores_kernel(
    const int* __restrict__ perm, const int* __restrict__ srcp,
    const int* __restrict__ tgtp, const float* __restrict__ ef,
    const unsigned short* __restrict__ Qa, const unsigned short* __restrict__ Ka,
    const unsigned short* __restrict__ WeaT, const float* __restrict__ bcomb,
    const float* __restrict__ A2p, const float* __restrict__ a2g,
    float* __restrict__ Pp, float* __restrict__ Z)
{
  __shared__ __align__(16) unsigned short efl[64 * 64];
  __shared__ __align__(16) float A2l[256 * 12];
  __shared__ __align__(16) float pl[4 * 64 * 8];
  __shared__ __align__(16) float bcl[256];
  __shared__ int srcl[64], tgtl[64];
  const int t = threadIdx.x;
  const int wid = t >> 6, lane = t & 63, quad = lane >> 4, l15 = lane & 15;
  const int eb = blockIdx.x * 64;

  {  // stage A2p (m-order) with padded stride
    const f32x4* sp = (const f32x4*)(A2p + t * 8);
    f32x4 x0 = sp[0], x1 = sp[1];
    *(f32x4*)&A2l[t * 12] = x0;
    *(f32x4*)&A2l[t * 12 + 4] = x1;
  }
  if (t < 64) srcl[t] = srcp[eb + t];
  else if (t < 128) tgtl[t - 64] = tgtp[eb + (t - 64)];
  else if (t < 192) ((f32x4*)bcl)[t - 128] = ((const f32x4*)bcomb)[t - 128];
  {  // stage ef rows (gathered via perm) -> bf16, slot-XOR swizzled
    int r = t >> 2, q4 = t & 3;
    int pe = perm[eb + r];
    const f32x4* sp = (const f32x4*)(ef + (size_t)pe * 64 + q4 * 16);
    f32x4 v0 = sp[0], v1 = sp[1], v2 = sp[2], v3 = sp[3];
    u16x8 w0 = { f2bf(v0[0]), f2bf(v0[1]), f2bf(v0[2]), f2bf(v0[3]),
                 f2bf(v1[0]), f2bf(v1[1]), f2bf(v1[2]), f2bf(v1[3]) };
    u16x8 w1 = { f2bf(v2[0]), f2bf(v2[1]), f2bf(v2[2]), f2bf(v2[3]),
                 f2bf(v3[0]), f2bf(v3[1]), f2bf(v3[2]), f2bf(v3[3]) };
    int s0_ = (2 * q4) ^ (r & 7), s1_ = (2 * q4 + 1) ^ (r & 7);
    *(u16x8*)&efl[r * 64 + s0_ * 8] = w0;
    *(u16x8*)&efl[r * 64 + s1_ * 8] = w1;
  }
  __syncthreads();

  // gathers initialize acc (C-in to MFMA).  Lane's 16 channels are the
  // contiguous Qa/Ka columns [wid*64 + quad*16, +16) thanks to chanperm.
  f32x4 acc[4][4];  // [ct][et]
  {
    const int cb = wid * 64 + quad * 16;
    #pragma unroll
    for (int eo = 0; eo < 2; ++eo) {
      u16x8 q0[2], q1[2], k0[2], k1[2];
      #pragma unroll
      for (int x = 0; x < 2; ++x) {
        int e = (eo * 2 + x) * 16 + l15;
        const unsigned short* qr = Qa + (size_t)srcl[e] * 256 + cb;
        const unsigned short* kr = Ka + (size_t)tgtl[e] * 256 + cb;
        q0[x] = *(const u16x8*)qr; q1[x] = *(const u16x8*)(qr + 8);
        k0[x] = *(const u16x8*)kr; k1[x] = *(const u16x8*)(kr + 8);
      }
      #pragma unroll
      for (int x = 0; x < 2; ++x) {
        int et = eo * 2 + x;
        #pragma unroll
        for (int r = 0; r < 4; ++r) {
          acc[0][et][r] = bf2f(q0[x][r])     + bf2f(k0[x][r]);
          acc[1][et][r] = bf2f(q0[x][4 + r]) + bf2f(k0[x][4 + r]);
          acc[2][et][r] = bf2f(q1[x][r])     + bf2f(k1[x][r]);
          acc[3][et][r] = bf2f(q1[x][4 + r]) + bf2f(k1[x][4 + r]);
        }
      }
    }
  }

  // MFMA: Ea accumulates on top of the gather sums
  {
    s16x8 af0[4], af1[4];
    #pragma unroll
    for (int ct = 0; ct < 4; ++ct) {
      int ch = wid * 64 + ct * 16 + l15;
      af0[ct] = *(const s16x8*)(WeaT + ch * 64 + quad * 8);
      af1[ct] = *(const s16x8*)(WeaT + ch * 64 + 32 + quad * 8);
    }
    #pragma unroll
    for (int et = 0; et < 4; ++et) {
      int e = et * 16 + l15;
      s16x8 b0 = *(const s16x8*)(efl + e * 64 + ((quad ^ (e & 7)) * 8));
      s16x8 b1 = *(const s16x8*)(efl + e * 64 + (((4 + quad) ^ (e & 7)) * 8));
      #pragma unroll
      for (int ct = 0; ct < 4; ++ct) {
        acc[ct][et] = __builtin_amdgcn_mfma_f32_16x16x32_bf16(af0[ct], b0, acc[ct][et], 0, 0, 0);
        acc[ct][et] = __builtin_amdgcn_mfma_f32_16x16x32_bf16(af1[ct], b1, acc[ct][et], 0, 0, 0);
      }
    }
  }

  // mid = lrelu(acc + bias); partials of mid @ A2 over this lane's 16 chans
  float part[4][8];
  #pragma unroll
  for (int i = 0; i < 4; ++i)
    #pragma unroll
    for (int j = 0; j < 8; ++j) part[i][j] = 0.f;
  #pragma unroll
  for (int ct = 0; ct < 4; ++ct) {
    int chb = wid * 64 + ct * 16 + quad * 4;
    f32x4 bc = *(const f32x4*)&bcl[chb];
    #pragma unroll
    for (int r = 0; r < 4; ++r) {
      f32x4 w0 = *(const f32x4*)&A2l[(chb + r) * 12];
      f32x4 w1 = *(const f32x4*)&A2l[(chb + r) * 12 + 4];
      #pragma unroll
      for (int et = 0; et < 4; ++et) {
        float m = lrelu(acc[ct][et][r] + bc[r]);
        part[et][0] += m * w0[0]; part[et][1] += m * w0[1];
        part[et][2] += m * w0[2]; part[et][3] += m * w0[3];
        part[et][4] += m * w1[0]; part[et][5] += m * w1[1];
        part[et][6] += m * w1[2]; part[et][7] += m * w1[3];
      }
    }
  }
  #pragma unroll
  for (int et = 0; et < 4; ++et)
    #pragma unroll
    for (int hh = 0; hh < 8; ++hh) {
      part[et][hh] += __shfl_xor(part[et][hh], 16);
      part[et][hh] += __shfl_xor(part[et][hh], 32);
    }
  if (quad == 0) {
    #pragma unroll
    for (int et = 0; et < 4; ++et) {
      f32x4 p0 = { part[et][0], part[et][1], part[et][2], part[et][3] };
      f32x4 p1 = { part[et][4], part[et][5], part[et][6], part[et][7] };
      int e = et * 16 + l15;
      *(f32x4*)&pl[(wid * 64 + e) * 8] = p0;
      *(f32x4*)&pl[(wid * 64 + e) * 8 + 4] = p1;
    }
  }
  __syncthreads();
  if (t < 64) {
    f32x4 t0 = {0.f, 0.f, 0.f, 0.f}, t1 = {0.f, 0.f, 0.f, 0.f};
    #pragma unroll
    for (int w2 = 0; w2 < 4; ++w2) {
      t0 += *(const f32x4*)&pl[(w2 * 64 + t) * 8];
      t1 += *(const f32x4*)&pl[(w2 * 64 + t) * 8 + 4];
    }
    float sacc = 0.f;
    #pragma unroll
    for (int j = 0; j < 4; ++j) {
      sacc += lrelu(t0[j] + a2g[j]);
      sacc += lrelu(t1[j] + a2g[4 + j]);
    }
    float p = __expf(sacc * 0.125f);
    Pp[eb + t] = p;
    #pragma unroll
    for (int d = 1; d < 64; d <<= 1) p += __shfl_xor(p, d);
    if (t == 0) atomicAdd(Z, p);
  }
}

// per-node accumulate + residual + LayerNorm.  4 nodes per WG (1 wave each);
// Pp/tgtp read CONTIGUOUSLY in CSR order.
__global__ __launch_bounds__(256) void scatter_ln_kernel(
    const int* __restrict__ startA, const float* __restrict__ Pp,
    const float* __restrict__ Zp, const int* __restrict__ tgtp,
    const unsigned short* __restrict__ vbuf, const float* __restrict__ hbuf,
    const float* __restrict__ gamma, const float* __restrict__ beta,
    float* __restrict__ out)
{
  const int wid = threadIdx.x >> 6, lane = threadIdx.x & 63;
  const int n = blockIdx.x * 4 + wid;
  const float invZ = 1.f / Zp[0];
  const int s0 = startA[n], s1 = startA[n + 1];
  float a0 = 0.f, a1_ = 0.f, a2_ = 0.f, a3_ = 0.f;
  int i = s0;
  for (; i + 1 < s1; i += 2) {
    float w0 = Pp[i], w1 = Pp[i + 1];
    int t0 = tgtp[i], t1 = tgtp[i + 1];
    u16x4 v0 = *(const u16x4*)(vbuf + (size_t)t0 * 256 + lane * 4);
    u16x4 v1 = *(const u16x4*)(vbuf + (size_t)t1 * 256 + lane * 4);
    w0 *= invZ; w1 *= invZ;
    a0 += w0 * bf2f(v0[0]) + w1 * bf2f(v1[0]);
    a1_ += w0 * bf2f(v0[1]) + w1 * bf2f(v1[1]);
    a2_ += w0 * bf2f(v0[2]) + w1 * bf2f(v1[2]);
    a3_ += w0 * bf2f(v0[3]) + w1 * bf2f(v1[3]);
  }
  if (i < s1) {
    float w0 = Pp[i] * invZ;
    int t0 = tgtp[i];
    u16x4 v0 = *(const u16x4*)(vbuf + (size_t)t0 * 256 + lane * 4);
    a0 += w0 * bf2f(v0[0]); a1_ += w0 * bf2f(v0[1]);
    a2_ += w0 * bf2f(v0[2]); a3_ += w0 * bf2f(v0[3]);
  }
  f32x4 hv = *(const f32x4*)(hbuf + (size_t)n * 256 + lane * 4);
  float x0 = hv[0] + a0, x1 = hv[1] + a1_, x2 = hv[2] + a2_, x3 = hv[3] + a3_;
  float sum = x0 + x1 + x2 + x3;
  float sq = x0 * x0 + x1 * x1 + x2 * x2 + x3 * x3;
  #pragma unroll
  for (int d = 1; d < 64; d <<= 1) { sum += __shfl_xor(sum, d); sq += __shfl_xor(sq, d); }
  float mu = sum * (1.f / 256.f);
  float var = sq * (1.f / 256.f) - mu * mu;
  float rstd = rsqrtf(var + 1e-5f);
  f32x4 g = *(const f32x4*)(gamma + lane * 4);
  f32x4 b = *(const f32x4*)(beta + lane * 4);
  f32x4 o;
  o[0] = (x0 - mu) * rstd * g[0] + b[0];
  o[1] = (x1 - mu) * rstd * g[1] + b[1];
  o[2] = (x2 - mu) * rstd * g[2] + b[2];
  o[3] = (x3 - mu) * rstd * g[3] + b[3];
  *(f32x4*)(out + (size_t)n * 256 + lane * 4) = o;
}

extern "C" void kernel_launch(void* const* d_in, const int* in_sizes, int n_in,
                              void* d_out, int out_size, void* d_ws, size_t ws_size,
                              hipStream_t stream)
{
  (void)in_sizes; (void)n_in; (void)out_size; (void)ws_size;
  const float* nf    = (const float*)d_in[0];
  const int*   eidx  = (const int*)  d_in[1];
  const float* ef    = (const float*)d_in[2];
  const float* Wn    = (const float*)d_in[3];
  const float* bn    = (const float*)d_in[4];
  const float* Wq    = (const float*)d_in[5];
  const float* bq    = (const float*)d_in[6];
  const float* Wk    = (const float*)d_in[7];
  const float* bk    = (const float*)d_in[8];
  const float* Wv    = (const float*)d_in[9];
  const float* bv    = (const float*)d_in[10];
  const float* We    = (const float*)d_in[11];
  const float* be    = (const float*)d_in[12];
  const float* A1    = (const float*)d_in[13];
  const float* a1    = (const float*)d_in[14];
  const float* A2    = (const float*)d_in[15];
  const float* a2    = (const float*)d_in[16];
  const float* gamma = (const float*)d_in[17];
  const float* beta  = (const float*)d_in[18];
  float* out = (float*)d_out;

  char* ws = (char*)d_ws;
  size_t off = 0;
  auto take = [&](size_t bytes) {
    size_t r = off; off += (bytes + 255) & ~(size_t)255; return r;
  };
  float* Z       = (float*)(ws + take(16));
  int*   deg     = (int*)  (ws + take((size_t)NN * 4));
  int*   startA  = (int*)  (ws + take((size_t)(NN + 1) * 4));
  int*   cursor  = (int*)  (ws + take((size_t)NN * 4));
  int*   perm    = (int*)  (ws + take((size_t)EE * 4));
  int*   srcp    = (int*)  (ws + take((size_t)EE * 4));
  int*   tgtp    = (int*)  (ws + take((size_t)EE * 4));
  float* Pp      = (float*)(ws + take((size_t)EE * 4));
  float* hbuf    = (float*)(ws + take((size_t)NN * DD * 4));
  unsigned short* vbuf  = (unsigned short*)(ws + take((size_t)NN * DD * 2));
  unsigned short* QaB   = (unsigned short*)(ws + take((size_t)NN * DD * 2));
  unsigned short* KaB   = (unsigned short*)(ws + take((size_t)NN * DD * 2));
  unsigned short* BcatT = (unsigned short*)(ws + take((size_t)1024 * 256 * 2));
  float* bcat    = (float*)(ws + take(1024 * 4));
  unsigned short* WeaT  = (unsigned short*)(ws + take((size_t)256 * 64 * 2));
  float* bcomb   = (float*)(ws + take(256 * 4));
  float* A2p     = (float*)(ws + take(256 * 8 * 4));
  unsigned short* nfb   = (unsigned short*)(ws + take((size_t)NN * DD * 2));

  // zero Z + deg
  hipMemsetAsync(d_ws, 0, 256 + (size_t)NN * 4, stream);

  prep_kernel<<<707, 256, 0, stream>>>(Wn, bn, Wq, bq, Wk, bk, Wv, bv,
                                       We, be, A1, a1, A2,
                                       BcatT, bcat, WeaT, bcomb, A2p);
  conv_hist_kernel<<<(NN * DD / 8) / 256, 256, 0, stream>>>(nf, nfb, eidx, deg);
  node_gemm_kernel<<<1024, 256, 0, stream>>>(nfb, BcatT, bcat, hbuf, vbuf, QaB, KaB);
  scan_kernel<<<1, 256, 0, stream>>>(deg, startA, cursor);
  perm_kernel<<<EE / 256, 256, 0, stream>>>(eidx, cursor, perm, srcp, tgtp);
  edge_scores_kernel<<<EE / 64, 256, 0, stream>>>(perm, srcp, tgtp, ef, QaB, KaB,
                                                  WeaT, bcomb, A2p, a2, Pp, Z);
  scatter_ln_kernel<<<NN / 4, 256, 0, stream>>>(startA, Pp, Z, tgtp, vbuf, hbuf,
                                                gamma, beta, out);
}